// Round 7
// baseline (4679.948 us; speedup 1.0000x reference)
//
#include <hip/hip_runtime.h>
#include <hip/hip_bf16.h>
#include <math.h>

// ---------------------------------------------------------------------------
// GeometricAugmentor forward — bf16 MFMA, r7:
//  * mgemm v4: reg-staged 2-deep prefetch + LDS double buffer.
//    Loads to VGPRs cross the barrier via register-dependency vmcnt (no
//    vmcnt(0) drain, unlike global_load_lds which r5/r6 proved serial).
//  * fragment-major conflict-free LDS layout (r5: 0 conflicts) kept.
//  * V-proj writes v^T directly; attn@V consumes padded attn rows (r4).
// ---------------------------------------------------------------------------

#define B_    64
#define NTOK  196
#define CCH   3
#define PDIM  768
#define DIM   512
#define MLP   2048
#define MROWS (B_ * NTOK)      // 12544
#define IMGHW 224
#define KPAD  224              // padded token count (attn cols / vT cols per batch)
#define VTLD  (B_ * KPAD)      // 14336

typedef __attribute__((ext_vector_type(8))) short bf16x8;
typedef __attribute__((ext_vector_type(4))) float f32x4;

static __device__ __forceinline__ unsigned short f2b(float f) {
    unsigned int x = __float_as_uint(f);
    unsigned int r = (x + 0x7FFFu + ((x >> 16) & 1u)) >> 16;
    return (unsigned short)r;
}
static __device__ __forceinline__ float softplusf(float x) {
    return fmaxf(x, 0.0f) + log1pf(expf(-fabsf(x)));
}

// ------------------------- patchify: img -> (M,768) bf16 -------------------
__global__ __launch_bounds__(256) void patchify_kernel(const float* __restrict__ img,
                                                       unsigned short* __restrict__ xp) {
    long idx = (long)blockIdx.x * blockDim.x + threadIdx.x;
    if (idx >= (long)MROWS * PDIM) return;
    int pd = (int)(idx % PDIM);
    long bn = idx / PDIM;
    int n = (int)(bn % NTOK);
    int b = (int)(bn / NTOK);
    int c = pd % 3;
    int p12 = pd / 3;
    int p1 = p12 >> 4, p2 = p12 & 15;
    int g1 = n / 14, g2 = n % 14;
    long src = (((long)b * CCH + c) * IMGHW + (g1 * 16 + p1)) * IMGHW + (g2 * 16 + p2);
    xp[idx] = f2b(img[src]);
}

// ---------------------- unpatchify: (M,768) f32 -> img ---------------------
__global__ __launch_bounds__(256) void unpatchify_kernel(const float* __restrict__ y,
                                                         float* __restrict__ out) {
    long idx = (long)blockIdx.x * blockDim.x + threadIdx.x;
    if (idx >= (long)B_ * CCH * IMGHW * IMGHW) return;
    int ww = (int)(idx % IMGHW);
    long r = idx / IMGHW;
    int hh = (int)(r % IMGHW);
    r /= IMGHW;
    int c = (int)(r % CCH);
    int b = (int)(r / CCH);
    int g1 = hh >> 4, p1 = hh & 15;
    int g2 = ww >> 4, p2 = ww & 15;
    int n = g1 * 14 + g2;
    int pd = (p1 * 16 + p2) * 3 + c;
    out[idx] = y[((long)b * NTOK + n) * PDIM + pd];
}

// -------- pos embedding: fused affine transform + random-Fourier (bf16) ----
__global__ __launch_bounds__(256) void pos_kernel(const float* __restrict__ Xc,
                                                  const float* __restrict__ Wfreq,
                                                  const float* __restrict__ A_noise,
                                                  const float* __restrict__ b_noise,
                                                  const float* __restrict__ A_mean,
                                                  const float* __restrict__ b_mean,
                                                  const float* __restrict__ A_std,
                                                  const float* __restrict__ b_std,
                                                  unsigned short* __restrict__ pos) {
    int bp = blockIdx.x;              // 0 .. 12543
    int b = bp / NTOK, p = bp % NTOK;
    int o = threadIdx.x;              // 0 .. 255
    float a00 = A_mean[0] + softplusf(A_std[0]) * A_noise[b * 4 + 0];
    float a01 = A_mean[1] + softplusf(A_std[1]) * A_noise[b * 4 + 1];
    float a10 = A_mean[2] + softplusf(A_std[2]) * A_noise[b * 4 + 2];
    float a11 = A_mean[3] + softplusf(A_std[3]) * A_noise[b * 4 + 3];
    float bv0 = b_mean[0] + softplusf(b_std[0]) * b_noise[b * 2 + 0];
    float bv1 = b_mean[1] + softplusf(b_std[1]) * b_noise[b * 2 + 1];
    float x0 = Xc[p * 2 + 0], x1 = Xc[p * 2 + 1];
    float xt0 = x0 * a00 + x1 * a10 + bv0;
    float xt1 = x0 * a01 + x1 * a11 + bv1;
    float proj = Wfreq[o * 2 + 0] * xt0 + Wfreq[o * 2 + 1] * xt1;
    float sv, cv;
    sincosf(proj, &sv, &cv);
    const float s = 0.08838834764831843f;   // sqrt(2/256)
    pos[(long)bp * DIM + o]       = f2b(s * cv);
    pos[(long)bp * DIM + 256 + o] = f2b(s * sv);
}

// ------ row softmax (len 196), f32 in -> bf16 out, padded rows of 224 ------
__global__ __launch_bounds__(64) void softmax_kernel(const float* __restrict__ dots,
                                                     unsigned short* __restrict__ attn) {
    long row = blockIdx.x;
    const float* p = dots + row * NTOK;
    unsigned short* q = attn + row * KPAD;
    int t = threadIdx.x;
    float v[4];
    float mx = -INFINITY;
    #pragma unroll
    for (int j = 0; j < 4; j++) {
        int i = t + j * 64;
        v[j] = (i < NTOK) ? p[i] : -INFINITY;
        mx = fmaxf(mx, v[j]);
    }
    #pragma unroll
    for (int off = 32; off >= 1; off >>= 1) mx = fmaxf(mx, __shfl_xor(mx, off));
    float sum = 0.f;
    #pragma unroll
    for (int j = 0; j < 4; j++) {
        int i = t + j * 64;
        v[j] = (i < NTOK) ? expf(v[j] - mx) : 0.f;
        sum += v[j];
    }
    #pragma unroll
    for (int off = 32; off >= 1; off >>= 1) sum += __shfl_xor(sum, off);
    float inv = 1.0f / sum;
    #pragma unroll
    for (int j = 0; j < 4; j++) {
        int i = t + j * 64;
        if (i < NTOK) q[i] = f2b(v[j] * inv);
        else if (i < KPAD) q[i] = 0;           // zero pad (exact-zero K columns)
    }
}

// ---------------- LayerNorm (512): f32 in -> bf16 out ----------------------
__global__ __launch_bounds__(128) void ln_kernel(const float* __restrict__ x,
                                                 const float* __restrict__ g,
                                                 const float* __restrict__ bb,
                                                 unsigned short* __restrict__ out) {
    long row = blockIdx.x;
    int t = threadIdx.x;
    float4 v = *(const float4*)(x + row * DIM + t * 4);
    float s = v.x + v.y + v.z + v.w;
    float q = v.x * v.x + v.y * v.y + v.z * v.z + v.w * v.w;
    #pragma unroll
    for (int off = 32; off >= 1; off >>= 1) {
        s += __shfl_xor(s, off);
        q += __shfl_xor(q, off);
    }
    __shared__ float red[4];
    int lane = t & 63, wv = t >> 6;
    if (lane == 0) { red[wv * 2] = s; red[wv * 2 + 1] = q; }
    __syncthreads();
    float S = red[0] + red[2], Q = red[1] + red[3];
    float mean = S * (1.0f / DIM);
    float var = Q * (1.0f / DIM) - mean * mean;
    float rs = rsqrtf(var + 1e-5f);
    float4 gg = *(const float4*)(g + t * 4);
    float4 bv = *(const float4*)(bb + t * 4);
    ushort4 o;
    o.x = f2b((v.x - mean) * rs * gg.x + bv.x);
    o.y = f2b((v.y - mean) * rs * gg.y + bv.y);
    o.z = f2b((v.z - mean) * rs * gg.z + bv.z);
    o.w = f2b((v.w - mean) * rs * gg.w + bv.w);
    *(ushort4*)(out + row * DIM + t * 4) = o;
}

// --------- fused weight transpose+convert: fp32 (R x C) -> bf16 (C x R) ----
struct TDesc {
    const float* in;
    unsigned short* out;
    int R, C, ld, cb, bbase, tx, trans;
};
struct TPack { TDesc d[19]; int n; };

__global__ __launch_bounds__(256) void wconv_kernel(TPack p) {
    __shared__ float t[32][33];
    int bid = blockIdx.x;
    int di = 0;
    for (int i = 1; i < p.n; ++i) if (bid >= p.d[i].bbase) di = i;
    TDesc d = p.d[di];
    int local = bid - d.bbase;
    int bx = local % d.tx, by = local / d.tx;
    int r0 = by * 32, c0 = bx * 32;
    int lx = threadIdx.x & 31, ly = threadIdx.x >> 5;
    if (d.trans) {
        #pragma unroll
        for (int i = 0; i < 4; i++) {
            int r = r0 + ly + i * 8, c = c0 + lx;
            t[ly + i * 8][lx] = (r < d.R && c < d.C) ? d.in[(long)r * d.ld + d.cb + c] : 0.f;
        }
        __syncthreads();
        #pragma unroll
        for (int i = 0; i < 4; i++) {
            int c = c0 + ly + i * 8, r = r0 + lx;
            if (c < d.C && r < d.R) d.out[(long)c * d.R + r] = f2b(t[lx][ly + i * 8]);
        }
    } else {
        #pragma unroll
        for (int i = 0; i < 4; i++) {
            int r = r0 + ly + i * 8, c = c0 + lx;
            if (r < d.R && c < d.C) d.out[(long)r * d.C + c] = f2b(d.in[(long)r * d.ld + d.cb + c]);
        }
    }
}

// ----------------------------- MFMA GEMM v4 --------------------------------
// C = act(A @ Bt^T * scale + bias) [+ residual]; A: M x K (lda), Bt: N x K (ldb).
// 128x128 tile, BK=32, 256 threads (4 waves, 2x2 of 64x64).
// Reg-staged 2-deep prefetch + LDS double buffer:
//   iter t invariant: LDS[cur]=tile t, regs[phase nxt]=tile t+1;
//   top of iter issues loads tile t+2 -> regs[cur] (reg-dep vmcnt, no drain).
// Fragment-major LDS layout [kquad][row][8 bf16]: element g at byte g*16,
// g = kquad*128 + row. Conflict-free (r5: 0 conflicts).
// grp>0: output col remap col -> (col/grp)*gstride + col%grp (batch padding).
template <bool GELU, bool RESID, bool WF32, bool WB16>
__global__ __launch_bounds__(256) void mgemm(const unsigned short* __restrict__ A,
                                             const unsigned short* __restrict__ Bt,
                                             const float* __restrict__ bias,
                                             const float* __restrict__ Rsd,
                                             float* __restrict__ Cf,
                                             unsigned short* __restrict__ Cb,
                                             int M, int N, int K,
                                             int lda, int ldb, int ldc,
                                             long bsA, long bsBt, long bsC,
                                             float scale, int grp, int gstride) {
    int bz = blockIdx.z;
    A  += bz * bsA;
    Bt += bz * bsBt;
    __shared__ __attribute__((aligned(1024))) unsigned short As[2][4096];  // 2 x 8 KB
    __shared__ __attribute__((aligned(1024))) unsigned short Bs[2][4096];  // 2 x 8 KB
    int m0 = blockIdx.y * 128, n0 = blockIdx.x * 128;
    int tid = threadIdx.x;
    int wave = tid >> 6, lane = tid & 63;
    int wm = (wave & 1) * 64, wn = (wave >> 1) * 64;
    int fr = lane & 15, fg = lane >> 4;

    // staging assignment: thread covers elements g1 (kquad 0..1) and g2 (2..3)
    int g1 = wave * 64 + lane;          // 0..255
    int g2 = g1 + 256;                  // 256..511
    int f1 = g1 >> 7, r1 = g1 & 127;
    int f2 = g2 >> 7, r2 = g2 & 127;
    int ra1 = m0 + r1; if (ra1 > M - 1) ra1 = M - 1;
    int ra2 = m0 + r2; if (ra2 > M - 1) ra2 = M - 1;
    int rb1 = n0 + r1; if (rb1 > N - 1) rb1 = N - 1;
    int rb2 = n0 + r2; if (rb2 > N - 1) rb2 = N - 1;
    const unsigned short* pa1 = A + (long)ra1 * lda + f1 * 8;
    const unsigned short* pa2 = A + (long)ra2 * lda + f2 * 8;
    const unsigned short* pb1 = Bt + (long)rb1 * ldb + f1 * 8;
    const unsigned short* pb2 = Bt + (long)rb2 * ldb + f2 * 8;

    f32x4 acc[4][4];
    #pragma unroll
    for (int i = 0; i < 4; i++)
        #pragma unroll
        for (int j = 0; j < 4; j++) acc[i][j] = (f32x4)0.f;

    int nt = K >> 5;
    // staged tiles: tile T lives in phase T&1
    bf16x8 sa1v[2], sa2v[2], sb1v[2], sb2v[2];
    sa1v[0] = *(const bf16x8*)(pa1);
    sa2v[0] = *(const bf16x8*)(pa2);
    sb1v[0] = *(const bf16x8*)(pb1);
    sb2v[0] = *(const bf16x8*)(pb2);
    if (nt > 1) {
        sa1v[1] = *(const bf16x8*)(pa1 + 32);
        sa2v[1] = *(const bf16x8*)(pa2 + 32);
        sb1v[1] = *(const bf16x8*)(pb1 + 32);
        sb2v[1] = *(const bf16x8*)(pb2 + 32);
    }
    // write tile 0 into LDS[0]
    *(bf16x8*)&As[0][g1 * 8] = sa1v[0];
    *(bf16x8*)&As[0][g2 * 8] = sa2v[0];
    *(bf16x8*)&Bs[0][g1 * 8] = sb1v[0];
    *(bf16x8*)&Bs[0][g2 * 8] = sb2v[0];
    __syncthreads();

    #pragma unroll 2
    for (int t = 0; t < nt; ++t) {
        int cur = t & 1, nxt = cur ^ 1;
        // issue loads for tile t+2 into phase cur (its old content is in LDS)
        if (t + 2 < nt) {
            int k0 = (t + 2) << 5;
            sa1v[cur] = *(const bf16x8*)(pa1 + k0);
            sa2v[cur] = *(const bf16x8*)(pa2 + k0);
            sb1v[cur] = *(const bf16x8*)(pb1 + k0);
            sb2v[cur] = *(const bf16x8*)(pb2 + k0);
        }
        // read fragments of tile t from LDS[cur]
        bf16x8 af[4], bfr[4];
        #pragma unroll
        for (int i = 0; i < 4; i++)
            af[i]  = *(const bf16x8*)&As[cur][(fg * 128 + wm + i * 16 + fr) * 8];
        #pragma unroll
        for (int j = 0; j < 4; j++)
            bfr[j] = *(const bf16x8*)&Bs[cur][(fg * 128 + wn + j * 16 + fr) * 8];
        // write tile t+1 (phase nxt, loaded last iter) into LDS[nxt];
        // compiler waits vmcnt only for those regs, newest loads stay in flight
        if (t + 1 < nt) {
            *(bf16x8*)&As[nxt][g1 * 8] = sa1v[nxt];
            *(bf16x8*)&As[nxt][g2 * 8] = sa2v[nxt];
            *(bf16x8*)&Bs[nxt][g1 * 8] = sb1v[nxt];
            *(bf16x8*)&Bs[nxt][g2 * 8] = sb2v[nxt];
        }
        #pragma unroll
        for (int i = 0; i < 4; i++)
            #pragma unroll
            for (int j = 0; j < 4; j++)
                acc[i][j] = __builtin_amdgcn_mfma_f32_16x16x32_bf16(af[i], bfr[j], acc[i][j], 0, 0, 0);
        __syncthreads();   // lgkmcnt drain: tile t+1 resident; all waves done
                           // reading LDS[cur]; reg loads (t+2) remain in flight
    }

    long cbase = (long)bz * bsC;
    #pragma unroll
    for (int i = 0; i < 4; i++) {
        int row = m0 + wm + i * 16 + fg * 4;
        #pragma unroll
        for (int j = 0; j < 4; j++) {
            int col = n0 + wn + j * 16 + fr;
            if (col >= N) continue;
            int ocol = (grp > 0) ? ((col / grp) * gstride + (col % grp)) : col;
            float bv = bias ? bias[col] : 0.f;
            #pragma unroll
            for (int r = 0; r < 4; r++) {
                if (row + r >= M) continue;
                float v = acc[i][j][r] * scale + bv;
                if (GELU) v = 0.5f * v * (1.0f + erff(v * 0.70710678118654752f));
                long ci = cbase + (long)(row + r) * ldc + ocol;
                if (RESID) v += Rsd[ci];
                if (WF32) Cf[ci] = v;
                if (WB16) Cb[ci] = f2b(v);
            }
        }
    }
}

// ---------------------------------------------------------------------------

extern "C" void kernel_launch(void* const* d_in, const int* in_sizes, int n_in,
                              void* d_out, int out_size, void* d_ws, size_t ws_size,
                              hipStream_t stream) {
    const float* img      = (const float*)d_in[0];
    const float* A_noise  = (const float*)d_in[2];
    const float* b_noise  = (const float*)d_in[3];
    const float* Wfreq    = (const float*)d_in[4];
    const float* Xc       = (const float*)d_in[5];
    const float* base_pos = (const float*)d_in[6];
    const float* A_mean   = (const float*)d_in[7];
    const float* b_mean   = (const float*)d_in[8];
    const float* A_std    = (const float*)d_in[9];
    const float* b_std    = (const float*)d_in[10];
    const float* Wpe      = (const float*)d_in[11];
    const float* bpe      = (const float*)d_in[12];
    const float* Wep      = (const float*)d_in[13];
    const float* bep      = (const float*)d_in[14];
    const float* ln1_g    = (const float*)d_in[15];
    const float* ln1_b    = (const float*)d_in[16];
    const float* Wqkv     = (const float*)d_in[17];
    const float* Wout     = (const float*)d_in[18];
    const float* bout     = (const float*)d_in[19];
    const float* ln2_g    = (const float*)d_in[20];
    const float* ln2_b    = (const float*)d_in[21];
    const float* Wff1     = (const float*)d_in[22];
    const float* bff1     = (const float*)d_in[23];
    const float* Wff2     = (const float*)d_in[24];
    const float* bff2     = (const float*)d_in[25];

    char* ws = (char*)d_ws;
    // ---- workspace layout (bytes) ----
    float*          x_f    = (float*)(ws + 0);                  // 12544x512 f32
    unsigned short* sb0    = (unsigned short*)(ws + 25690112);  // xn16 / out16
    unsigned short* attn16 = (unsigned short*)(ws + 38535168);  // 64 x 196 x 224
    unsigned short* vT     = (unsigned short*)(ws + 44154880);  // 512 x 14336
    unsigned short* xb16   = (unsigned short*)(ws + 58834944);  // 12544x512
    unsigned short* h1     = (unsigned short*)(ws + 71680000);  // 12544x2048 -> ends 123060224
    // carved from h1 region (dead before first FF1):
    unsigned short* pat16  = (unsigned short*)(ws + 71680000);              // 12544x768
    unsigned short* pos16  = (unsigned short*)(ws + 90947584);              // 12544x512
    float*          dots   = (float*)(ws + 103792640);                      // 12544x196 f32
    float*          y_f    = (float*)(ws + 71680000);           // 12544x768 f32 (h1 dead)
    // weights (bf16, transposed to N x K)
    char* wp = ws + 123060224;
    unsigned short* WpeT   = (unsigned short*)(wp);                     // 512x768
    unsigned short* WqkvT  = (unsigned short*)(wp + 786432);            // 4 x 512x512
    unsigned short* WoutT  = (unsigned short*)(wp + 2883584);           // 4 x 512x512
    unsigned short* Wff1T  = (unsigned short*)(wp + 4980736);           // 4 x 2048x512
    unsigned short* Wff2T  = (unsigned short*)(wp + 13369344);          // 4 x 512x2048
    unsigned short* WepT   = (unsigned short*)(wp + 21757952);          // 768x512
    unsigned short* bp16   = (unsigned short*)(wp + 22544384);          // 196x512
    // end of workspace use: 145,805,312 bytes

    const float SCALE = 0.044194173824159216f;     // 512^-0.5

    // 0) zero vT once per launch (pad cols must be exact zeros)
    hipMemsetAsync(vT, 0, (size_t)512 * VTLD * 2, stream);

    // 0b) weight conversion / transposition, one fused kernel
    {
        TPack p; int bb = 0, di = 0;
        auto add = [&](const float* in, unsigned short* out, int R, int C, int ld, int cb, int tr) {
            TDesc d; d.in = in; d.out = out; d.R = R; d.C = C; d.ld = ld; d.cb = cb;
            d.trans = tr; d.tx = (C + 31) / 32; d.bbase = bb;
            bb += d.tx * ((R + 31) / 32);
            p.d[di++] = d;
        };
        add(Wpe, WpeT, 768, 512, 512, 0, 1);
        for (int l = 0; l < 4; l++) add(Wqkv + (long)l * 512 * 1536, WqkvT + (long)l * 512 * 512, 512, 512, 1536, 1024, 1);
        for (int l = 0; l < 4; l++) add(Wout + (long)l * 512 * 512, WoutT + (long)l * 512 * 512, 512, 512, 512, 0, 1);
        for (int l = 0; l < 4; l++) add(Wff1 + (long)l * 512 * 2048, Wff1T + (long)l * 2048 * 512, 512, 2048, 2048, 0, 1);
        for (int l = 0; l < 4; l++) add(Wff2 + (long)l * 2048 * 512, Wff2T + (long)l * 512 * 2048, 2048, 512, 512, 0, 1);
        add(Wep, WepT, 512, 768, 768, 0, 1);
        add(base_pos, bp16, 196, 512, 512, 0, 0);
        p.n = di;
        wconv_kernel<<<dim3(bb), dim3(256), 0, stream>>>(p);
    }

    // 1) patchify -> pat16
    patchify_kernel<<<dim3((MROWS * PDIM + 255) / 256), dim3(256), 0, stream>>>(img, pat16);
    // 2) patch embed: pat16 @ WpeT^T + bpe -> x_f
    mgemm<false, false, true, false><<<dim3(4, 98), dim3(256), 0, stream>>>(
        pat16, WpeT, bpe, nullptr, x_f, nullptr, MROWS, DIM, PDIM, PDIM, PDIM, DIM,
        0, 0, 0, 1.0f, 0, 0);
    // 3) positional embedding -> pos16
    pos_kernel<<<dim3(MROWS), dim3(256), 0, stream>>>(
        Xc, Wfreq, A_noise, b_noise, A_mean, b_mean, A_std, b_std, pos16);
    // 4) dots = pos @ base_pos^T * SCALE -> dots (f32)
    mgemm<false, false, true, false><<<dim3(2, 98), dim3(256), 0, stream>>>(
        pos16, bp16, nullptr, nullptr, dots, nullptr, MROWS, NTOK, DIM, DIM, DIM, NTOK,
        0, 0, 0, SCALE, 0, 0);
    // 5) softmax -> attn16 (bf16, rows padded to 224 with zeros)
    softmax_kernel<<<dim3(MROWS), dim3(64), 0, stream>>>(dots, attn16);

    for (int l = 0; l < 4; l++) {
        // LN1: x_f -> sb0 (xn16)
        ln_kernel<<<dim3(MROWS), dim3(128), 0, stream>>>(x_f, ln1_g + l * DIM, ln1_b + l * DIM, sb0);
        // vT = Wv^T @ xn^T : A = WqkvT_l (512x512), Bt = xn (12544x512)
        mgemm<false, false, false, true><<<dim3(98, 4), dim3(256), 0, stream>>>(
            WqkvT + (long)l * 512 * 512, sb0, nullptr, nullptr, nullptr, vT,
            512, MROWS, DIM, DIM, DIM, VTLD, 0, 0, 0, 1.0f, NTOK, KPAD);
        // out_b = attn_b @ vT_b^T : A = attn16_b (196x224), Bt = vT_b (512 rows, ld VTLD)
        mgemm<false, false, false, true><<<dim3(4, 2, B_), dim3(256), 0, stream>>>(
            attn16, vT, nullptr, nullptr, nullptr, sb0,
            NTOK, DIM, KPAD, KPAD, VTLD, DIM,
            (long)NTOK * KPAD, (long)KPAD, (long)NTOK * DIM, 1.0f, 0, 0);
        // x = out @ Wout^T + bout -> x_f
        mgemm<false, false, true, false><<<dim3(4, 98), dim3(256), 0, stream>>>(
            sb0, WoutT + (long)l * 512 * 512, bout + l * DIM, nullptr, x_f, nullptr,
            MROWS, DIM, DIM, DIM, DIM, DIM, 0, 0, 0, 1.0f, 0, 0);
        // LN2: x_f -> sb0
        ln_kernel<<<dim3(MROWS), dim3(128), 0, stream>>>(x_f, ln2_g + l * DIM, ln2_b + l * DIM, sb0);
        // h1 = gelu(xn2 @ Wff1^T + bff1) (bf16)
        mgemm<true, false, false, true><<<dim3(16, 98), dim3(256), 0, stream>>>(
            sb0, Wff1T + (long)l * 2048 * 512, bff1 + l * MLP, nullptr, nullptr, h1,
            MROWS, MLP, DIM, DIM, DIM, MLP, 0, 0, 0, 1.0f, 0, 0);
        // x = h1 @ Wff2^T + bff2 + x  (dual write: x_f f32 + xb16 bf16)
        mgemm<false, true, true, true><<<dim3(4, 98), dim3(256), 0, stream>>>(
            h1, Wff2T + (long)l * 512 * 2048, bff2 + l * DIM, x_f, x_f, xb16,
            MROWS, DIM, MLP, MLP, MLP, DIM, 0, 0, 0, 1.0f, 0, 0);
    }

    // final projection: xb16 @ Wep^T + bep -> y_f
    mgemm<false, false, true, false><<<dim3(6, 98), dim3(256), 0, stream>>>(
        xb16, WepT, bep, nullptr, y_f, nullptr, MROWS, PDIM, DIM, DIM, DIM, PDIM,
        0, 0, 0, 1.0f, 0, 0);
    // unpatchify -> d_out
    unpatchify_kernel<<<dim3(((long)B_ * CCH * IMGHW * IMGHW + 255) / 256), dim3(256), 0, stream>>>(
        y_f, (float*)d_out);
}

// Round 9
// 1645.302 us; speedup vs baseline: 2.8444x; 2.8444x over previous
//
#include <hip/hip_runtime.h>
#include <hip/hip_bf16.h>
#include <math.h>

// ---------------------------------------------------------------------------
// GeometricAugmentor forward — bf16 MFMA, r9 (resubmit of r8; GPU timeout):
//  * mgemm v5: r4's reg-staged single-buffer structure (compiler-pipelined,
//    empirically 90us FF1) + r5's fragment-major conflict-free LDS layout
//    (verified 0 bank conflicts). NO stage arrays (r7 scratch lesson, rule #20).
//  * V-proj writes v^T directly; attn@V consumes padded attn rows (r4).
// ---------------------------------------------------------------------------

#define B_    64
#define NTOK  196
#define CCH   3
#define PDIM  768
#define DIM   512
#define MLP   2048
#define MROWS (B_ * NTOK)      // 12544
#define IMGHW 224
#define KPAD  224              // padded token count (attn cols / vT cols per batch)
#define VTLD  (B_ * KPAD)      // 14336

typedef __attribute__((ext_vector_type(8))) short bf16x8;
typedef __attribute__((ext_vector_type(4))) float f32x4;

static __device__ __forceinline__ unsigned short f2b(float f) {
    unsigned int x = __float_as_uint(f);
    unsigned int r = (x + 0x7FFFu + ((x >> 16) & 1u)) >> 16;
    return (unsigned short)r;
}
static __device__ __forceinline__ float softplusf(float x) {
    return fmaxf(x, 0.0f) + log1pf(expf(-fabsf(x)));
}

// ------------------------- patchify: img -> (M,768) bf16 -------------------
__global__ __launch_bounds__(256) void patchify_kernel(const float* __restrict__ img,
                                                       unsigned short* __restrict__ xp) {
    long idx = (long)blockIdx.x * blockDim.x + threadIdx.x;
    if (idx >= (long)MROWS * PDIM) return;
    int pd = (int)(idx % PDIM);
    long bn = idx / PDIM;
    int n = (int)(bn % NTOK);
    int b = (int)(bn / NTOK);
    int c = pd % 3;
    int p12 = pd / 3;
    int p1 = p12 >> 4, p2 = p12 & 15;
    int g1 = n / 14, g2 = n % 14;
    long src = (((long)b * CCH + c) * IMGHW + (g1 * 16 + p1)) * IMGHW + (g2 * 16 + p2);
    xp[idx] = f2b(img[src]);
}

// ---------------------- unpatchify: (M,768) f32 -> img ---------------------
__global__ __launch_bounds__(256) void unpatchify_kernel(const float* __restrict__ y,
                                                         float* __restrict__ out) {
    long idx = (long)blockIdx.x * blockDim.x + threadIdx.x;
    if (idx >= (long)B_ * CCH * IMGHW * IMGHW) return;
    int ww = (int)(idx % IMGHW);
    long r = idx / IMGHW;
    int hh = (int)(r % IMGHW);
    r /= IMGHW;
    int c = (int)(r % CCH);
    int b = (int)(r / CCH);
    int g1 = hh >> 4, p1 = hh & 15;
    int g2 = ww >> 4, p2 = ww & 15;
    int n = g1 * 14 + g2;
    int pd = (p1 * 16 + p2) * 3 + c;
    out[idx] = y[((long)b * NTOK + n) * PDIM + pd];
}

// -------- pos embedding: fused affine transform + random-Fourier (bf16) ----
__global__ __launch_bounds__(256) void pos_kernel(const float* __restrict__ Xc,
                                                  const float* __restrict__ Wfreq,
                                                  const float* __restrict__ A_noise,
                                                  const float* __restrict__ b_noise,
                                                  const float* __restrict__ A_mean,
                                                  const float* __restrict__ b_mean,
                                                  const float* __restrict__ A_std,
                                                  const float* __restrict__ b_std,
                                                  unsigned short* __restrict__ pos) {
    int bp = blockIdx.x;              // 0 .. 12543
    int b = bp / NTOK, p = bp % NTOK;
    int o = threadIdx.x;              // 0 .. 255
    float a00 = A_mean[0] + softplusf(A_std[0]) * A_noise[b * 4 + 0];
    float a01 = A_mean[1] + softplusf(A_std[1]) * A_noise[b * 4 + 1];
    float a10 = A_mean[2] + softplusf(A_std[2]) * A_noise[b * 4 + 2];
    float a11 = A_mean[3] + softplusf(A_std[3]) * A_noise[b * 4 + 3];
    float bv0 = b_mean[0] + softplusf(b_std[0]) * b_noise[b * 2 + 0];
    float bv1 = b_mean[1] + softplusf(b_std[1]) * b_noise[b * 2 + 1];
    float x0 = Xc[p * 2 + 0], x1 = Xc[p * 2 + 1];
    float xt0 = x0 * a00 + x1 * a10 + bv0;
    float xt1 = x0 * a01 + x1 * a11 + bv1;
    float proj = Wfreq[o * 2 + 0] * xt0 + Wfreq[o * 2 + 1] * xt1;
    float sv, cv;
    sincosf(proj, &sv, &cv);
    const float s = 0.08838834764831843f;   // sqrt(2/256)
    pos[(long)bp * DIM + o]       = f2b(s * cv);
    pos[(long)bp * DIM + 256 + o] = f2b(s * sv);
}

// ------ row softmax (len 196), f32 in -> bf16 out, padded rows of 224 ------
__global__ __launch_bounds__(64) void softmax_kernel(const float* __restrict__ dots,
                                                     unsigned short* __restrict__ attn) {
    long row = blockIdx.x;
    const float* p = dots + row * NTOK;
    unsigned short* q = attn + row * KPAD;
    int t = threadIdx.x;
    float v[4];
    float mx = -INFINITY;
    #pragma unroll
    for (int j = 0; j < 4; j++) {
        int i = t + j * 64;
        v[j] = (i < NTOK) ? p[i] : -INFINITY;
        mx = fmaxf(mx, v[j]);
    }
    #pragma unroll
    for (int off = 32; off >= 1; off >>= 1) mx = fmaxf(mx, __shfl_xor(mx, off));
    float sum = 0.f;
    #pragma unroll
    for (int j = 0; j < 4; j++) {
        int i = t + j * 64;
        v[j] = (i < NTOK) ? expf(v[j] - mx) : 0.f;
        sum += v[j];
    }
    #pragma unroll
    for (int off = 32; off >= 1; off >>= 1) sum += __shfl_xor(sum, off);
    float inv = 1.0f / sum;
    #pragma unroll
    for (int j = 0; j < 4; j++) {
        int i = t + j * 64;
        if (i < NTOK) q[i] = f2b(v[j] * inv);
        else if (i < KPAD) q[i] = 0;           // zero pad (exact-zero K columns)
    }
}

// ---------------- LayerNorm (512): f32 in -> bf16 out ----------------------
__global__ __launch_bounds__(128) void ln_kernel(const float* __restrict__ x,
                                                 const float* __restrict__ g,
                                                 const float* __restrict__ bb,
                                                 unsigned short* __restrict__ out) {
    long row = blockIdx.x;
    int t = threadIdx.x;
    float4 v = *(const float4*)(x + row * DIM + t * 4);
    float s = v.x + v.y + v.z + v.w;
    float q = v.x * v.x + v.y * v.y + v.z * v.z + v.w * v.w;
    #pragma unroll
    for (int off = 32; off >= 1; off >>= 1) {
        s += __shfl_xor(s, off);
        q += __shfl_xor(q, off);
    }
    __shared__ float red[4];
    int lane = t & 63, wv = t >> 6;
    if (lane == 0) { red[wv * 2] = s; red[wv * 2 + 1] = q; }
    __syncthreads();
    float S = red[0] + red[2], Q = red[1] + red[3];
    float mean = S * (1.0f / DIM);
    float var = Q * (1.0f / DIM) - mean * mean;
    float rs = rsqrtf(var + 1e-5f);
    float4 gg = *(const float4*)(g + t * 4);
    float4 bv = *(const float4*)(bb + t * 4);
    ushort4 o;
    o.x = f2b((v.x - mean) * rs * gg.x + bv.x);
    o.y = f2b((v.y - mean) * rs * gg.y + bv.y);
    o.z = f2b((v.z - mean) * rs * gg.z + bv.z);
    o.w = f2b((v.w - mean) * rs * gg.w + bv.w);
    *(ushort4*)(out + row * DIM + t * 4) = o;
}

// --------- fused weight transpose+convert: fp32 (R x C) -> bf16 (C x R) ----
struct TDesc {
    const float* in;
    unsigned short* out;
    int R, C, ld, cb, bbase, tx, trans;
};
struct TPack { TDesc d[19]; int n; };

__global__ __launch_bounds__(256) void wconv_kernel(TPack p) {
    __shared__ float t[32][33];
    int bid = blockIdx.x;
    int di = 0;
    for (int i = 1; i < p.n; ++i) if (bid >= p.d[i].bbase) di = i;
    TDesc d = p.d[di];
    int local = bid - d.bbase;
    int bx = local % d.tx, by = local / d.tx;
    int r0 = by * 32, c0 = bx * 32;
    int lx = threadIdx.x & 31, ly = threadIdx.x >> 5;
    if (d.trans) {
        #pragma unroll
        for (int i = 0; i < 4; i++) {
            int r = r0 + ly + i * 8, c = c0 + lx;
            t[ly + i * 8][lx] = (r < d.R && c < d.C) ? d.in[(long)r * d.ld + d.cb + c] : 0.f;
        }
        __syncthreads();
        #pragma unroll
        for (int i = 0; i < 4; i++) {
            int c = c0 + ly + i * 8, r = r0 + lx;
            if (c < d.C && r < d.R) d.out[(long)c * d.R + r] = f2b(t[lx][ly + i * 8]);
        }
    } else {
        #pragma unroll
        for (int i = 0; i < 4; i++) {
            int r = r0 + ly + i * 8, c = c0 + lx;
            if (r < d.R && c < d.C) d.out[(long)r * d.C + c] = f2b(d.in[(long)r * d.ld + d.cb + c]);
        }
    }
}

// ----------------------------- MFMA GEMM v5 --------------------------------
// C = act(A @ Bt^T * scale + bias) [+ residual]; A: M x K (lda), Bt: N x K (ldb).
// 128x128 tile, BK=32, 256 threads (4 waves, 2x2 of 64x64).
// Staging: named-register loads at loop top (compiler software-pipelines
// them across the barrier), single-buffered LDS, fragment-major layout
// [kquad][row][8 bf16] (element g at byte g*16, g = kquad*128 + row):
// conflict-free for both the b128 staging writes and fragment reads.
// grp>0: output col remap col -> (col/grp)*gstride + col%grp (batch padding).
template <bool GELU, bool RESID, bool WF32, bool WB16>
__global__ __launch_bounds__(256) void mgemm(const unsigned short* __restrict__ A,
                                             const unsigned short* __restrict__ Bt,
                                             const float* __restrict__ bias,
                                             const float* __restrict__ Rsd,
                                             float* __restrict__ Cf,
                                             unsigned short* __restrict__ Cb,
                                             int M, int N, int K,
                                             int lda, int ldb, int ldc,
                                             long bsA, long bsBt, long bsC,
                                             float scale, int grp, int gstride) {
    int bz = blockIdx.z;
    A  += bz * bsA;
    Bt += bz * bsBt;
    __shared__ __attribute__((aligned(1024))) unsigned short As[4096];  // 8 KB
    __shared__ __attribute__((aligned(1024))) unsigned short Bs[4096];  // 8 KB
    int m0 = blockIdx.y * 128, n0 = blockIdx.x * 128;
    int tid = threadIdx.x;
    int wave = tid >> 6, lane = tid & 63;
    int wm = (wave & 1) * 64, wn = (wave >> 1) * 64;
    int fr = lane & 15, fg = lane >> 4;

    // staging assignment: thread covers elements g1 (kquad 0..1) and g2 (2..3)
    int g1 = wave * 64 + lane;          // 0..255
    int g2 = g1 + 256;                  // 256..511
    int f1 = g1 >> 7, r1 = g1 & 127;
    int f2 = g2 >> 7, r2 = g2 & 127;
    int ra1 = m0 + r1; if (ra1 > M - 1) ra1 = M - 1;
    int ra2 = m0 + r2; if (ra2 > M - 1) ra2 = M - 1;
    int rb1 = n0 + r1; if (rb1 > N - 1) rb1 = N - 1;
    int rb2 = n0 + r2; if (rb2 > N - 1) rb2 = N - 1;
    const unsigned short* pa1 = A + (long)ra1 * lda + f1 * 8;
    const unsigned short* pa2 = A + (long)ra2 * lda + f2 * 8;
    const unsigned short* pb1 = Bt + (long)rb1 * ldb + f1 * 8;
    const unsigned short* pb2 = Bt + (long)rb2 * ldb + f2 * 8;

    f32x4 acc[4][4];
    #pragma unroll
    for (int i = 0; i < 4; i++)
        #pragma unroll
        for (int j = 0; j < 4; j++) acc[i][j] = (f32x4)0.f;

    for (int k0 = 0; k0 < K; k0 += 32) {
        // named-register staging loads (rule #20: no arrays)
        bf16x8 va1 = *(const bf16x8*)(pa1 + k0);
        bf16x8 va2 = *(const bf16x8*)(pa2 + k0);
        bf16x8 vb1 = *(const bf16x8*)(pb1 + k0);
        bf16x8 vb2 = *(const bf16x8*)(pb2 + k0);
        __syncthreads();                 // all waves done reading previous tile
        *(bf16x8*)&As[g1 * 8] = va1;
        *(bf16x8*)&As[g2 * 8] = va2;
        *(bf16x8*)&Bs[g1 * 8] = vb1;
        *(bf16x8*)&Bs[g2 * 8] = vb2;
        __syncthreads();                 // tile resident
        bf16x8 af[4], bfr[4];
        #pragma unroll
        for (int i = 0; i < 4; i++)
            af[i]  = *(const bf16x8*)&As[(fg * 128 + wm + i * 16 + fr) * 8];
        #pragma unroll
        for (int j = 0; j < 4; j++)
            bfr[j] = *(const bf16x8*)&Bs[(fg * 128 + wn + j * 16 + fr) * 8];
        #pragma unroll
        for (int i = 0; i < 4; i++)
            #pragma unroll
            for (int j = 0; j < 4; j++)
                acc[i][j] = __builtin_amdgcn_mfma_f32_16x16x32_bf16(af[i], bfr[j], acc[i][j], 0, 0, 0);
    }

    long cbase = (long)bz * bsC;
    #pragma unroll
    for (int i = 0; i < 4; i++) {
        int row = m0 + wm + i * 16 + fg * 4;
        #pragma unroll
        for (int j = 0; j < 4; j++) {
            int col = n0 + wn + j * 16 + fr;
            if (col >= N) continue;
            int ocol = (grp > 0) ? ((col / grp) * gstride + (col % grp)) : col;
            float bv = bias ? bias[col] : 0.f;
            #pragma unroll
            for (int r = 0; r < 4; r++) {
                if (row + r >= M) continue;
                float v = acc[i][j][r] * scale + bv;
                if (GELU) v = 0.5f * v * (1.0f + erff(v * 0.70710678118654752f));
                long ci = cbase + (long)(row + r) * ldc + ocol;
                if (RESID) v += Rsd[ci];
                if (WF32) Cf[ci] = v;
                if (WB16) Cb[ci] = f2b(v);
            }
        }
    }
}

// ---------------------------------------------------------------------------

extern "C" void kernel_launch(void* const* d_in, const int* in_sizes, int n_in,
                              void* d_out, int out_size, void* d_ws, size_t ws_size,
                              hipStream_t stream) {
    const float* img      = (const float*)d_in[0];
    const float* A_noise  = (const float*)d_in[2];
    const float* b_noise  = (const float*)d_in[3];
    const float* Wfreq    = (const float*)d_in[4];
    const float* Xc       = (const float*)d_in[5];
    const float* base_pos = (const float*)d_in[6];
    const float* A_mean   = (const float*)d_in[7];
    const float* b_mean   = (const float*)d_in[8];
    const float* A_std    = (const float*)d_in[9];
    const float* b_std    = (const float*)d_in[10];
    const float* Wpe      = (const float*)d_in[11];
    const float* bpe      = (const float*)d_in[12];
    const float* Wep      = (const float*)d_in[13];
    const float* bep      = (const float*)d_in[14];
    const float* ln1_g    = (const float*)d_in[15];
    const float* ln1_b    = (const float*)d_in[16];
    const float* Wqkv     = (const float*)d_in[17];
    const float* Wout     = (const float*)d_in[18];
    const float* bout     = (const float*)d_in[19];
    const float* ln2_g    = (const float*)d_in[20];
    const float* ln2_b    = (const float*)d_in[21];
    const float* Wff1     = (const float*)d_in[22];
    const float* bff1     = (const float*)d_in[23];
    const float* Wff2     = (const float*)d_in[24];
    const float* bff2     = (const float*)d_in[25];

    char* ws = (char*)d_ws;
    // ---- workspace layout (bytes) ----
    float*          x_f    = (float*)(ws + 0);                  // 12544x512 f32
    unsigned short* sb0    = (unsigned short*)(ws + 25690112);  // xn16 / out16
    unsigned short* attn16 = (unsigned short*)(ws + 38535168);  // 64 x 196 x 224
    unsigned short* vT     = (unsigned short*)(ws + 44154880);  // 512 x 14336
    unsigned short* xb16   = (unsigned short*)(ws + 58834944);  // 12544x512
    unsigned short* h1     = (unsigned short*)(ws + 71680000);  // 12544x2048 -> ends 123060224
    // carved from h1 region (dead before first FF1):
    unsigned short* pat16  = (unsigned short*)(ws + 71680000);              // 12544x768
    unsigned short* pos16  = (unsigned short*)(ws + 90947584);              // 12544x512
    float*          dots   = (float*)(ws + 103792640);                      // 12544x196 f32
    float*          y_f    = (float*)(ws + 71680000);           // 12544x768 f32 (h1 dead)
    // weights (bf16, transposed to N x K)
    char* wp = ws + 123060224;
    unsigned short* WpeT   = (unsigned short*)(wp);                     // 512x768
    unsigned short* WqkvT  = (unsigned short*)(wp + 786432);            // 4 x 512x512
    unsigned short* WoutT  = (unsigned short*)(wp + 2883584);           // 4 x 512x512
    unsigned short* Wff1T  = (unsigned short*)(wp + 4980736);           // 4 x 2048x512
    unsigned short* Wff2T  = (unsigned short*)(wp + 13369344);          // 4 x 512x2048
    unsigned short* WepT   = (unsigned short*)(wp + 21757952);          // 768x512
    unsigned short* bp16   = (unsigned short*)(wp + 22544384);          // 196x512
    // end of workspace use: 145,805,312 bytes

    const float SCALE = 0.044194173824159216f;     // 512^-0.5

    // 0) zero vT once per launch (pad cols must be exact zeros)
    hipMemsetAsync(vT, 0, (size_t)512 * VTLD * 2, stream);

    // 0b) weight conversion / transposition, one fused kernel
    {
        TPack p; int bb = 0, di = 0;
        auto add = [&](const float* in, unsigned short* out, int R, int C, int ld, int cb, int tr) {
            TDesc d; d.in = in; d.out = out; d.R = R; d.C = C; d.ld = ld; d.cb = cb;
            d.trans = tr; d.tx = (C + 31) / 32; d.bbase = bb;
            bb += d.tx * ((R + 31) / 32);
            p.d[di++] = d;
        };
        add(Wpe, WpeT, 768, 512, 512, 0, 1);
        for (int l = 0; l < 4; l++) add(Wqkv + (long)l * 512 * 1536, WqkvT + (long)l * 512 * 512, 512, 512, 1536, 1024, 1);
        for (int l = 0; l < 4; l++) add(Wout + (long)l * 512 * 512, WoutT + (long)l * 512 * 512, 512, 512, 512, 0, 1);
        for (int l = 0; l < 4; l++) add(Wff1 + (long)l * 512 * 2048, Wff1T + (long)l * 2048 * 512, 512, 2048, 2048, 0, 1);
        for (int l = 0; l < 4; l++) add(Wff2 + (long)l * 2048 * 512, Wff2T + (long)l * 512 * 2048, 2048, 512, 512, 0, 1);
        add(Wep, WepT, 512, 768, 768, 0, 1);
        add(base_pos, bp16, 196, 512, 512, 0, 0);
        p.n = di;
        wconv_kernel<<<dim3(bb), dim3(256), 0, stream>>>(p);
    }

    // 1) patchify -> pat16
    patchify_kernel<<<dim3((MROWS * PDIM + 255) / 256), dim3(256), 0, stream>>>(img, pat16);
    // 2) patch embed: pat16 @ WpeT^T + bpe -> x_f
    mgemm<false, false, true, false><<<dim3(4, 98), dim3(256), 0, stream>>>(
        pat16, WpeT, bpe, nullptr, x_f, nullptr, MROWS, DIM, PDIM, PDIM, PDIM, DIM,
        0, 0, 0, 1.0f, 0, 0);
    // 3) positional embedding -> pos16
    pos_kernel<<<dim3(MROWS), dim3(256), 0, stream>>>(
        Xc, Wfreq, A_noise, b_noise, A_mean, b_mean, A_std, b_std, pos16);
    // 4) dots = pos @ base_pos^T * SCALE -> dots (f32)
    mgemm<false, false, true, false><<<dim3(2, 98), dim3(256), 0, stream>>>(
        pos16, bp16, nullptr, nullptr, dots, nullptr, MROWS, NTOK, DIM, DIM, DIM, NTOK,
        0, 0, 0, SCALE, 0, 0);
    // 5) softmax -> attn16 (bf16, rows padded to 224 with zeros)
    softmax_kernel<<<dim3(MROWS), dim3(64), 0, stream>>>(dots, attn16);

    for (int l = 0; l < 4; l++) {
        // LN1: x_f -> sb0 (xn16)
        ln_kernel<<<dim3(MROWS), dim3(128), 0, stream>>>(x_f, ln1_g + l * DIM, ln1_b + l * DIM, sb0);
        // vT = Wv^T @ xn^T : A = WqkvT_l (512x512), Bt = xn (12544x512)
        mgemm<false, false, false, true><<<dim3(98, 4), dim3(256), 0, stream>>>(
            WqkvT + (long)l * 512 * 512, sb0, nullptr, nullptr, nullptr, vT,
            512, MROWS, DIM, DIM, DIM, VTLD, 0, 0, 0, 1.0f, NTOK, KPAD);
        // out_b = attn_b @ vT_b^T : A = attn16_b (196x224), Bt = vT_b (512 rows, ld VTLD)
        mgemm<false, false, false, true><<<dim3(4, 2, B_), dim3(256), 0, stream>>>(
            attn16, vT, nullptr, nullptr, nullptr, sb0,
            NTOK, DIM, KPAD, KPAD, VTLD, DIM,
            (long)NTOK * KPAD, (long)KPAD, (long)NTOK * DIM, 1.0f, 0, 0);
        // x = out @ Wout^T + bout -> x_f
        mgemm<false, false, true, false><<<dim3(4, 98), dim3(256), 0, stream>>>(
            sb0, WoutT + (long)l * 512 * 512, bout + l * DIM, nullptr, x_f, nullptr,
            MROWS, DIM, DIM, DIM, DIM, DIM, 0, 0, 0, 1.0f, 0, 0);
        // LN2: x_f -> sb0
        ln_kernel<<<dim3(MROWS), dim3(128), 0, stream>>>(x_f, ln2_g + l * DIM, ln2_b + l * DIM, sb0);
        // h1 = gelu(xn2 @ Wff1^T + bff1) (bf16)
        mgemm<true, false, false, true><<<dim3(16, 98), dim3(256), 0, stream>>>(
            sb0, Wff1T + (long)l * 2048 * 512, bff1 + l * MLP, nullptr, nullptr, h1,
            MROWS, MLP, DIM, DIM, DIM, MLP, 0, 0, 0, 1.0f, 0, 0);
        // x = h1 @ Wff2^T + bff2 + x  (dual write: x_f f32 + xb16 bf16)
        mgemm<false, true, true, true><<<dim3(4, 98), dim3(256), 0, stream>>>(
            h1, Wff2T + (long)l * 512 * 2048, bff2 + l * DIM, x_f, x_f, xb16,
            MROWS, DIM, MLP, MLP, MLP, DIM, 0, 0, 0, 1.0f, 0, 0);
    }

    // final projection: xb16 @ Wep^T + bep -> y_f
    mgemm<false, false, true, false><<<dim3(6, 98), dim3(256), 0, stream>>>(
        xb16, WepT, bep, nullptr, y_f, nullptr, MROWS, PDIM, DIM, DIM, DIM, PDIM,
        0, 0, 0, 1.0f, 0, 0);
    // unpatchify -> d_out
    unpatchify_kernel<<<dim3(((long)B_ * CCH * IMGHW * IMGHW + 255) / 256), dim3(256), 0, stream>>>(
        y_f, (float*)d_out);
}

// Round 13
// 1431.738 us; speedup vs baseline: 3.2687x; 1.1492x over previous
//
#include <hip/hip_runtime.h>
#include <hip/hip_bf16.h>
#include <math.h>

// ---------------------------------------------------------------------------
// GeometricAugmentor forward — bf16 MFMA, r13 (resubmit; r10-r12 GPU timeouts):
//  * mgemm v6: r4's COALESCED staging (thread = one row, two adjacent 16B
//    loads; wave = 32 fully-consumed lines) + fragment-major conflict-free
//    LDS layout (r5/r9: 0 conflicts). r9 post-mortem: per-lane-row staging
//    doubled VMEM line traffic per wave -> 853 GB/s vs r4's 1163.
//  * V-proj writes v^T directly; attn@V consumes padded attn rows (r4).
// ---------------------------------------------------------------------------

#define B_    64
#define NTOK  196
#define CCH   3
#define PDIM  768
#define DIM   512
#define MLP   2048
#define MROWS (B_ * NTOK)      // 12544
#define IMGHW 224
#define KPAD  224              // padded token count (attn cols / vT cols per batch)
#define VTLD  (B_ * KPAD)      // 14336

typedef __attribute__((ext_vector_type(8))) short bf16x8;
typedef __attribute__((ext_vector_type(4))) float f32x4;

static __device__ __forceinline__ unsigned short f2b(float f) {
    unsigned int x = __float_as_uint(f);
    unsigned int r = (x + 0x7FFFu + ((x >> 16) & 1u)) >> 16;
    return (unsigned short)r;
}
static __device__ __forceinline__ float softplusf(float x) {
    return fmaxf(x, 0.0f) + log1pf(expf(-fabsf(x)));
}

// ------------------------- patchify: img -> (M,768) bf16 -------------------
__global__ __launch_bounds__(256) void patchify_kernel(const float* __restrict__ img,
                                                       unsigned short* __restrict__ xp) {
    long idx = (long)blockIdx.x * blockDim.x + threadIdx.x;
    if (idx >= (long)MROWS * PDIM) return;
    int pd = (int)(idx % PDIM);
    long bn = idx / PDIM;
    int n = (int)(bn % NTOK);
    int b = (int)(bn / NTOK);
    int c = pd % 3;
    int p12 = pd / 3;
    int p1 = p12 >> 4, p2 = p12 & 15;
    int g1 = n / 14, g2 = n % 14;
    long src = (((long)b * CCH + c) * IMGHW + (g1 * 16 + p1)) * IMGHW + (g2 * 16 + p2);
    xp[idx] = f2b(img[src]);
}

// ---------------------- unpatchify: (M,768) f32 -> img ---------------------
__global__ __launch_bounds__(256) void unpatchify_kernel(const float* __restrict__ y,
                                                         float* __restrict__ out) {
    long idx = (long)blockIdx.x * blockDim.x + threadIdx.x;
    if (idx >= (long)B_ * CCH * IMGHW * IMGHW) return;
    int ww = (int)(idx % IMGHW);
    long r = idx / IMGHW;
    int hh = (int)(r % IMGHW);
    r /= IMGHW;
    int c = (int)(r % CCH);
    int b = (int)(r / CCH);
    int g1 = hh >> 4, p1 = hh & 15;
    int g2 = ww >> 4, p2 = ww & 15;
    int n = g1 * 14 + g2;
    int pd = (p1 * 16 + p2) * 3 + c;
    out[idx] = y[((long)b * NTOK + n) * PDIM + pd];
}

// -------- pos embedding: fused affine transform + random-Fourier (bf16) ----
__global__ __launch_bounds__(256) void pos_kernel(const float* __restrict__ Xc,
                                                  const float* __restrict__ Wfreq,
                                                  const float* __restrict__ A_noise,
                                                  const float* __restrict__ b_noise,
                                                  const float* __restrict__ A_mean,
                                                  const float* __restrict__ b_mean,
                                                  const float* __restrict__ A_std,
                                                  const float* __restrict__ b_std,
                                                  unsigned short* __restrict__ pos) {
    int bp = blockIdx.x;              // 0 .. 12543
    int b = bp / NTOK, p = bp % NTOK;
    int o = threadIdx.x;              // 0 .. 255
    float a00 = A_mean[0] + softplusf(A_std[0]) * A_noise[b * 4 + 0];
    float a01 = A_mean[1] + softplusf(A_std[1]) * A_noise[b * 4 + 1];
    float a10 = A_mean[2] + softplusf(A_std[2]) * A_noise[b * 4 + 2];
    float a11 = A_mean[3] + softplusf(A_std[3]) * A_noise[b * 4 + 3];
    float bv0 = b_mean[0] + softplusf(b_std[0]) * b_noise[b * 2 + 0];
    float bv1 = b_mean[1] + softplusf(b_std[1]) * b_noise[b * 2 + 1];
    float x0 = Xc[p * 2 + 0], x1 = Xc[p * 2 + 1];
    float xt0 = x0 * a00 + x1 * a10 + bv0;
    float xt1 = x0 * a01 + x1 * a11 + bv1;
    float proj = Wfreq[o * 2 + 0] * xt0 + Wfreq[o * 2 + 1] * xt1;
    float sv, cv;
    sincosf(proj, &sv, &cv);
    const float s = 0.08838834764831843f;   // sqrt(2/256)
    pos[(long)bp * DIM + o]       = f2b(s * cv);
    pos[(long)bp * DIM + 256 + o] = f2b(s * sv);
}

// ------ row softmax (len 196), f32 in -> bf16 out, padded rows of 224 ------
__global__ __launch_bounds__(64) void softmax_kernel(const float* __restrict__ dots,
                                                     unsigned short* __restrict__ attn) {
    long row = blockIdx.x;
    const float* p = dots + row * NTOK;
    unsigned short* q = attn + row * KPAD;
    int t = threadIdx.x;
    float v[4];
    float mx = -INFINITY;
    #pragma unroll
    for (int j = 0; j < 4; j++) {
        int i = t + j * 64;
        v[j] = (i < NTOK) ? p[i] : -INFINITY;
        mx = fmaxf(mx, v[j]);
    }
    #pragma unroll
    for (int off = 32; off >= 1; off >>= 1) mx = fmaxf(mx, __shfl_xor(mx, off));
    float sum = 0.f;
    #pragma unroll
    for (int j = 0; j < 4; j++) {
        int i = t + j * 64;
        v[j] = (i < NTOK) ? expf(v[j] - mx) : 0.f;
        sum += v[j];
    }
    #pragma unroll
    for (int off = 32; off >= 1; off >>= 1) sum += __shfl_xor(sum, off);
    float inv = 1.0f / sum;
    #pragma unroll
    for (int j = 0; j < 4; j++) {
        int i = t + j * 64;
        if (i < NTOK) q[i] = f2b(v[j] * inv);
        else if (i < KPAD) q[i] = 0;           // zero pad (exact-zero K columns)
    }
}

// ---------------- LayerNorm (512): f32 in -> bf16 out ----------------------
__global__ __launch_bounds__(128) void ln_kernel(const float* __restrict__ x,
                                                 const float* __restrict__ g,
                                                 const float* __restrict__ bb,
                                                 unsigned short* __restrict__ out) {
    long row = blockIdx.x;
    int t = threadIdx.x;
    float4 v = *(const float4*)(x + row * DIM + t * 4);
    float s = v.x + v.y + v.z + v.w;
    float q = v.x * v.x + v.y * v.y + v.z * v.z + v.w * v.w;
    #pragma unroll
    for (int off = 32; off >= 1; off >>= 1) {
        s += __shfl_xor(s, off);
        q += __shfl_xor(q, off);
    }
    __shared__ float red[4];
    int lane = t & 63, wv = t >> 6;
    if (lane == 0) { red[wv * 2] = s; red[wv * 2 + 1] = q; }
    __syncthreads();
    float S = red[0] + red[2], Q = red[1] + red[3];
    float mean = S * (1.0f / DIM);
    float var = Q * (1.0f / DIM) - mean * mean;
    float rs = rsqrtf(var + 1e-5f);
    float4 gg = *(const float4*)(g + t * 4);
    float4 bv = *(const float4*)(bb + t * 4);
    ushort4 o;
    o.x = f2b((v.x - mean) * rs * gg.x + bv.x);
    o.y = f2b((v.y - mean) * rs * gg.y + bv.y);
    o.z = f2b((v.z - mean) * rs * gg.z + bv.z);
    o.w = f2b((v.w - mean) * rs * gg.w + bv.w);
    *(ushort4*)(out + row * DIM + t * 4) = o;
}

// --------- fused weight transpose+convert: fp32 (R x C) -> bf16 (C x R) ----
struct TDesc {
    const float* in;
    unsigned short* out;
    int R, C, ld, cb, bbase, tx, trans;
};
struct TPack { TDesc d[19]; int n; };

__global__ __launch_bounds__(256) void wconv_kernel(TPack p) {
    __shared__ float t[32][33];
    int bid = blockIdx.x;
    int di = 0;
    for (int i = 1; i < p.n; ++i) if (bid >= p.d[i].bbase) di = i;
    TDesc d = p.d[di];
    int local = bid - d.bbase;
    int bx = local % d.tx, by = local / d.tx;
    int r0 = by * 32, c0 = bx * 32;
    int lx = threadIdx.x & 31, ly = threadIdx.x >> 5;
    if (d.trans) {
        #pragma unroll
        for (int i = 0; i < 4; i++) {
            int r = r0 + ly + i * 8, c = c0 + lx;
            t[ly + i * 8][lx] = (r < d.R && c < d.C) ? d.in[(long)r * d.ld + d.cb + c] : 0.f;
        }
        __syncthreads();
        #pragma unroll
        for (int i = 0; i < 4; i++) {
            int c = c0 + ly + i * 8, r = r0 + lx;
            if (c < d.C && r < d.R) d.out[(long)c * d.R + r] = f2b(t[lx][ly + i * 8]);
        }
    } else {
        #pragma unroll
        for (int i = 0; i < 4; i++) {
            int r = r0 + ly + i * 8, c = c0 + lx;
            if (r < d.R && c < d.C) d.out[(long)r * d.C + c] = f2b(d.in[(long)r * d.ld + d.cb + c]);
        }
    }
}

// ----------------------------- MFMA GEMM v6 --------------------------------
// C = act(A @ Bt^T * scale + bias) [+ residual]; A: M x K (lda), Bt: N x K (ldb).
// 128x128 tile, BK=32, 256 threads (4 waves, 2x2 of 64x64).
// Staging (r4-coalesced): thread (ar=tid>>1, ah=tid&1) loads row m0+ar,
// two ADJACENT 16B chunks (kquads 2ah, 2ah+1) -> wave covers 32 full 64B
// lines. LDS fragment-major layout: element unit u = kquad*128 + row at
// byte u*16; writes land as contiguous 512B blocks per instruction
// (bank-uniform); fragment reads conflict-free (r5/r9: 0 conflicts).
// grp>0: output col remap col -> (col/grp)*gstride + col%grp (batch padding).
template <bool GELU, bool RESID, bool WF32, bool WB16>
__global__ __launch_bounds__(256) void mgemm(const unsigned short* __restrict__ A,
                                             const unsigned short* __restrict__ Bt,
                                             const float* __restrict__ bias,
                                             const float* __restrict__ Rsd,
                                             float* __restrict__ Cf,
                                             unsigned short* __restrict__ Cb,
                                             int M, int N, int K,
                                             int lda, int ldb, int ldc,
                                             long bsA, long bsBt, long bsC,
                                             float scale, int grp, int gstride) {
    int bz = blockIdx.z;
    A  += bz * bsA;
    Bt += bz * bsBt;
    __shared__ __attribute__((aligned(1024))) unsigned short As[4096];  // 8 KB
    __shared__ __attribute__((aligned(1024))) unsigned short Bs[4096];  // 8 KB
    int m0 = blockIdx.y * 128, n0 = blockIdx.x * 128;
    int tid = threadIdx.x;
    int wave = tid >> 6, lane = tid & 63;
    int wm = (wave & 1) * 64, wn = (wave >> 1) * 64;
    int fr = lane & 15, fg = lane >> 4;

    // staging: thread (ar,ah) covers row ar, kquads {2ah, 2ah+1}
    int ar = tid >> 1, ah = tid & 1;
    int raA = m0 + ar; if (raA > M - 1) raA = M - 1;
    int rbB = n0 + ar; if (rbB > N - 1) rbB = N - 1;
    const unsigned short* pa = A + (long)raA * lda + ah * 16;
    const unsigned short* pb = Bt + (long)rbB * ldb + ah * 16;
    int u0 = (2 * ah) * 128 + ar;       // LDS unit for first kquad
    // second kquad unit = u0 + 128

    f32x4 acc[4][4];
    #pragma unroll
    for (int i = 0; i < 4; i++)
        #pragma unroll
        for (int j = 0; j < 4; j++) acc[i][j] = (f32x4)0.f;

    for (int k0 = 0; k0 < K; k0 += 32) {
        // named-register staging loads, two adjacent 16B per matrix (coalesced)
        bf16x8 va0 = *(const bf16x8*)(pa + k0);
        bf16x8 va1 = *(const bf16x8*)(pa + k0 + 8);
        bf16x8 vb0 = *(const bf16x8*)(pb + k0);
        bf16x8 vb1 = *(const bf16x8*)(pb + k0 + 8);
        __syncthreads();                 // all waves done reading previous tile
        *(bf16x8*)&As[u0 * 8]         = va0;
        *(bf16x8*)&As[(u0 + 128) * 8] = va1;
        *(bf16x8*)&Bs[u0 * 8]         = vb0;
        *(bf16x8*)&Bs[(u0 + 128) * 8] = vb1;
        __syncthreads();                 // tile resident
        bf16x8 af[4], bfr[4];
        #pragma unroll
        for (int i = 0; i < 4; i++)
            af[i]  = *(const bf16x8*)&As[(fg * 128 + wm + i * 16 + fr) * 8];
        #pragma unroll
        for (int j = 0; j < 4; j++)
            bfr[j] = *(const bf16x8*)&Bs[(fg * 128 + wn + j * 16 + fr) * 8];
        #pragma unroll
        for (int i = 0; i < 4; i++)
            #pragma unroll
            for (int j = 0; j < 4; j++)
                acc[i][j] = __builtin_amdgcn_mfma_f32_16x16x32_bf16(af[i], bfr[j], acc[i][j], 0, 0, 0);
    }

    long cbase = (long)bz * bsC;
    #pragma unroll
    for (int i = 0; i < 4; i++) {
        int row = m0 + wm + i * 16 + fg * 4;
        #pragma unroll
        for (int j = 0; j < 4; j++) {
            int col = n0 + wn + j * 16 + fr;
            if (col >= N) continue;
            int ocol = (grp > 0) ? ((col / grp) * gstride + (col % grp)) : col;
            float bv = bias ? bias[col] : 0.f;
            #pragma unroll
            for (int r = 0; r < 4; r++) {
                if (row + r >= M) continue;
                float v = acc[i][j][r] * scale + bv;
                if (GELU) v = 0.5f * v * (1.0f + erff(v * 0.70710678118654752f));
                long ci = cbase + (long)(row + r) * ldc + ocol;
                if (RESID) v += Rsd[ci];
                if (WF32) Cf[ci] = v;
                if (WB16) Cb[ci] = f2b(v);
            }
        }
    }
}

// ---------------------------------------------------------------------------

extern "C" void kernel_launch(void* const* d_in, const int* in_sizes, int n_in,
                              void* d_out, int out_size, void* d_ws, size_t ws_size,
                              hipStream_t stream) {
    const float* img      = (const float*)d_in[0];
    const float* A_noise  = (const float*)d_in[2];
    const float* b_noise  = (const float*)d_in[3];
    const float* Wfreq    = (const float*)d_in[4];
    const float* Xc       = (const float*)d_in[5];
    const float* base_pos = (const float*)d_in[6];
    const float* A_mean   = (const float*)d_in[7];
    const float* b_mean   = (const float*)d_in[8];
    const float* A_std    = (const float*)d_in[9];
    const float* b_std    = (const float*)d_in[10];
    const float* Wpe      = (const float*)d_in[11];
    const float* bpe      = (const float*)d_in[12];
    const float* Wep      = (const float*)d_in[13];
    const float* bep      = (const float*)d_in[14];
    const float* ln1_g    = (const float*)d_in[15];
    const float* ln1_b    = (const float*)d_in[16];
    const float* Wqkv     = (const float*)d_in[17];
    const float* Wout     = (const float*)d_in[18];
    const float* bout     = (const float*)d_in[19];
    const float* ln2_g    = (const float*)d_in[20];
    const float* ln2_b    = (const float*)d_in[21];
    const float* Wff1     = (const float*)d_in[22];
    const float* bff1     = (const float*)d_in[23];
    const float* Wff2     = (const float*)d_in[24];
    const float* bff2     = (const float*)d_in[25];

    char* ws = (char*)d_ws;
    // ---- workspace layout (bytes) ----
    float*          x_f    = (float*)(ws + 0);                  // 12544x512 f32
    unsigned short* sb0    = (unsigned short*)(ws + 25690112);  // xn16 / out16
    unsigned short* attn16 = (unsigned short*)(ws + 38535168);  // 64 x 196 x 224
    unsigned short* vT     = (unsigned short*)(ws + 44154880);  // 512 x 14336
    unsigned short* xb16   = (unsigned short*)(ws + 58834944);  // 12544x512
    unsigned short* h1     = (unsigned short*)(ws + 71680000);  // 12544x2048 -> ends 123060224
    // carved from h1 region (dead before first FF1):
    unsigned short* pat16  = (unsigned short*)(ws + 71680000);              // 12544x768
    unsigned short* pos16  = (unsigned short*)(ws + 90947584);              // 12544x512
    float*          dots   = (float*)(ws + 103792640);                      // 12544x196 f32
    float*          y_f    = (float*)(ws + 71680000);           // 12544x768 f32 (h1 dead)
    // weights (bf16, transposed to N x K)
    char* wp = ws + 123060224;
    unsigned short* WpeT   = (unsigned short*)(wp);                     // 512x768
    unsigned short* WqkvT  = (unsigned short*)(wp + 786432);            // 4 x 512x512
    unsigned short* WoutT  = (unsigned short*)(wp + 2883584);           // 4 x 512x512
    unsigned short* Wff1T  = (unsigned short*)(wp + 4980736);           // 4 x 2048x512
    unsigned short* Wff2T  = (unsigned short*)(wp + 13369344);          // 4 x 512x2048
    unsigned short* WepT   = (unsigned short*)(wp + 21757952);          // 768x512
    unsigned short* bp16   = (unsigned short*)(wp + 22544384);          // 196x512
    // end of workspace use: 145,805,312 bytes

    const float SCALE = 0.044194173824159216f;     // 512^-0.5

    // 0) zero vT once per launch (pad cols must be exact zeros)
    hipMemsetAsync(vT, 0, (size_t)512 * VTLD * 2, stream);

    // 0b) weight conversion / transposition, one fused kernel
    {
        TPack p; int bb = 0, di = 0;
        auto add = [&](const float* in, unsigned short* out, int R, int C, int ld, int cb, int tr) {
            TDesc d; d.in = in; d.out = out; d.R = R; d.C = C; d.ld = ld; d.cb = cb;
            d.trans = tr; d.tx = (C + 31) / 32; d.bbase = bb;
            bb += d.tx * ((R + 31) / 32);
            p.d[di++] = d;
        };
        add(Wpe, WpeT, 768, 512, 512, 0, 1);
        for (int l = 0; l < 4; l++) add(Wqkv + (long)l * 512 * 1536, WqkvT + (long)l * 512 * 512, 512, 512, 1536, 1024, 1);
        for (int l = 0; l < 4; l++) add(Wout + (long)l * 512 * 512, WoutT + (long)l * 512 * 512, 512, 512, 512, 0, 1);
        for (int l = 0; l < 4; l++) add(Wff1 + (long)l * 512 * 2048, Wff1T + (long)l * 2048 * 512, 512, 2048, 2048, 0, 1);
        for (int l = 0; l < 4; l++) add(Wff2 + (long)l * 2048 * 512, Wff2T + (long)l * 512 * 2048, 2048, 512, 512, 0, 1);
        add(Wep, WepT, 512, 768, 768, 0, 1);
        add(base_pos, bp16, 196, 512, 512, 0, 0);
        p.n = di;
        wconv_kernel<<<dim3(bb), dim3(256), 0, stream>>>(p);
    }

    // 1) patchify -> pat16
    patchify_kernel<<<dim3((MROWS * PDIM + 255) / 256), dim3(256), 0, stream>>>(img, pat16);
    // 2) patch embed: pat16 @ WpeT^T + bpe -> x_f
    mgemm<false, false, true, false><<<dim3(4, 98), dim3(256), 0, stream>>>(
        pat16, WpeT, bpe, nullptr, x_f, nullptr, MROWS, DIM, PDIM, PDIM, PDIM, DIM,
        0, 0, 0, 1.0f, 0, 0);
    // 3) positional embedding -> pos16
    pos_kernel<<<dim3(MROWS), dim3(256), 0, stream>>>(
        Xc, Wfreq, A_noise, b_noise, A_mean, b_mean, A_std, b_std, pos16);
    // 4) dots = pos @ base_pos^T * SCALE -> dots (f32)
    mgemm<false, false, true, false><<<dim3(2, 98), dim3(256), 0, stream>>>(
        pos16, bp16, nullptr, nullptr, dots, nullptr, MROWS, NTOK, DIM, DIM, DIM, NTOK,
        0, 0, 0, SCALE, 0, 0);
    // 5) softmax -> attn16 (bf16, rows padded to 224 with zeros)
    softmax_kernel<<<dim3(MROWS), dim3(64), 0, stream>>>(dots, attn16);

    for (int l = 0; l < 4; l++) {
        // LN1: x_f -> sb0 (xn16)
        ln_kernel<<<dim3(MROWS), dim3(128), 0, stream>>>(x_f, ln1_g + l * DIM, ln1_b + l * DIM, sb0);
        // vT = Wv^T @ xn^T : A = WqkvT_l (512x512), Bt = xn (12544x512)
        mgemm<false, false, false, true><<<dim3(98, 4), dim3(256), 0, stream>>>(
            WqkvT + (long)l * 512 * 512, sb0, nullptr, nullptr, nullptr, vT,
            512, MROWS, DIM, DIM, DIM, VTLD, 0, 0, 0, 1.0f, NTOK, KPAD);
        // out_b = attn_b @ vT_b^T : A = attn16_b (196x224), Bt = vT_b (512 rows, ld VTLD)
        mgemm<false, false, false, true><<<dim3(4, 2, B_), dim3(256), 0, stream>>>(
            attn16, vT, nullptr, nullptr, nullptr, sb0,
            NTOK, DIM, KPAD, KPAD, VTLD, DIM,
            (long)NTOK * KPAD, (long)KPAD, (long)NTOK * DIM, 1.0f, 0, 0);
        // x = out @ Wout^T + bout -> x_f
        mgemm<false, false, true, false><<<dim3(4, 98), dim3(256), 0, stream>>>(
            sb0, WoutT + (long)l * 512 * 512, bout + l * DIM, nullptr, x_f, nullptr,
            MROWS, DIM, DIM, DIM, DIM, DIM, 0, 0, 0, 1.0f, 0, 0);
        // LN2: x_f -> sb0
        ln_kernel<<<dim3(MROWS), dim3(128), 0, stream>>>(x_f, ln2_g + l * DIM, ln2_b + l * DIM, sb0);
        // h1 = gelu(xn2 @ Wff1^T + bff1) (bf16)
        mgemm<true, false, false, true><<<dim3(16, 98), dim3(256), 0, stream>>>(
            sb0, Wff1T + (long)l * 2048 * 512, bff1 + l * MLP, nullptr, nullptr, h1,
            MROWS, MLP, DIM, DIM, DIM, MLP, 0, 0, 0, 1.0f, 0, 0);
        // x = h1 @ Wff2^T + bff2 + x  (dual write: x_f f32 + xb16 bf16)
        mgemm<false, true, true, true><<<dim3(4, 98), dim3(256), 0, stream>>>(
            h1, Wff2T + (long)l * 512 * 2048, bff2 + l * DIM, x_f, x_f, xb16,
            MROWS, DIM, MLP, MLP, MLP, DIM, 0, 0, 0, 1.0f, 0, 0);
    }

    // final projection: xb16 @ Wep^T + bep -> y_f
    mgemm<false, false, true, false><<<dim3(6, 98), dim3(256), 0, stream>>>(
        xb16, WepT, bep, nullptr, y_f, nullptr, MROWS, PDIM, DIM, DIM, DIM, PDIM,
        0, 0, 0, 1.0f, 0, 0);
    // unpatchify -> d_out
    unpatchify_kernel<<<dim3(((long)B_ * CCH * IMGHW * IMGHW + 255) / 256), dim3(256), 0, stream>>>(
        y_f, (float*)d_out);
}